// Round 5
// baseline (269.055 us; speedup 1.0000x reference)
//
#include <hip/hip_runtime.h>

// spike_seq: (T=1024, B=16384, 2) fp32, values EXACTLY 0.0f / 1.0f.
// w_exc=(1,2)={0.7,1.0}; w_inh=-1.0.
// Outputs flat-concat: spk_rec (T*B) ++ mem_rec (T*B), fp32.
//
// 3-phase chunked scan over 2-bit packed inputs (bit-exact reconstruction):
//  P0 pack: x -> 2-bit codes, uint4-grouped per neuron (134 MB read, 4 MB wr)
//  P1 scan: serial carry scan, 1 wave/CU. R5: dynamic 16-iter loop with an
//           8 KB I$-resident body (R4's ~30 KB unrolled windows thrashed I$
//           with no co-resident wave to hide I-fetch), uint4 double-buffer
//           prefetch (128-step lookahead >> LLC latency), 15 VALU/step.
//  P2 emit: per-chunk replay, stream 134 MB out with PLAIN stores (R4's NT
//           stores bypass L2 write aggregation; nothing left to protect).
#define T_LEN  1024
#define B_N    16384
#define CHUNKS 32
#define CLEN   (T_LEN / CHUNKS)   // 32 steps per emit chunk
#define TPW    16                 // timesteps per packed u32 (2 bits each)
#define NTC    (T_LEN / TPW)      // 64 words per neuron
#define GR     (NTC / 4)          // 16 uint4 groups per neuron

// cbits layout: uint4 group g of neuron b at cb4[g*B_N + b]
//   word (4g+j) of neuron b = dword cbits[(g*B_N + b)*4 + j]

// One scan step, contract(off) except the two provably-exact fmas.
// Reference rounding: cur_exc = fl(fl(x0*w0) + fl(x1*w1)); since x0,x1 in
// {0,1}, both products are exact -> fmaf(x0, w0, x1*w1) is bit-identical.
// inh/mem updates keep separate mul+add (products inexact there).
__device__ __forceinline__ void neuron_step_core(float x0, float x1,
                                                 float w0, float w1, float wi,
                                                 float& mem, float& inh) {
#pragma clang fp contract(off)
  const float cur_exc = __builtin_fmaf(x0, w0, x1 * w1);  // exact products
  inh = 0.6f * inh + x0;
  const float cur = cur_exc + wi * inh;
  const bool reset = (mem - 1.0f > 0.0f);   // prev-mem threshold (exact test)
  const float m2 = 0.9f * mem + cur;
  mem = reset ? (m2 - 1.0f) : m2;           // reset*THRESHOLD, THRESHOLD=1
}

// ---- Phase 0: pack x into 2-bit codes (interleaved uint4 layout). ----
__global__ __launch_bounds__(256) void FMFM_pack(
    const float* __restrict__ x, unsigned* __restrict__ cbits) {
  const int tid = blockIdx.x * 256 + threadIdx.x;   // 524288 threads
  const int b2  = tid & (B_N / 2 - 1);              // neuron pair (8192)
  const int tc  = tid >> 13;                        // word index 0..NTC-1
  const float4* __restrict__ xp = (const float4*)x; // (T, B/2) float4

  unsigned bits0 = 0, bits1 = 0;
#pragma unroll
  for (int u = 0; u < TPW; ++u) {
    const int t = tc * TPW + u;
    const float4 v = xp[(size_t)t * (B_N / 2) + b2];
    bits0 |= ((v.x != 0.0f) ? 1u : 0u) << (2 * u);
    bits0 |= ((v.y != 0.0f) ? 2u : 0u) << (2 * u);
    bits1 |= ((v.z != 0.0f) ? 1u : 0u) << (2 * u);
    bits1 |= ((v.w != 0.0f) ? 2u : 0u) << (2 * u);
  }
  // Scattered dword writes into the uint4 layout (4 MB through L2 — cheap).
  const size_t base = ((size_t)(tc >> 2) * B_N + 2 * b2) * 4 + (tc & 3);
  cbits[base]     = bits0;   // neuron 2*b2
  cbits[base + 4] = bits1;   // neuron 2*b2+1
}

// ---- Phase 1: serial carry scan. 256 blocks x 64 thr = 1 wave/CU. ----
__global__ __launch_bounds__(64, 1) void FMFM_scan(
    const unsigned* __restrict__ cbits, const float* __restrict__ w_exc,
    const float* __restrict__ w_inh, float* __restrict__ carry) {
#pragma clang fp contract(off)
  const int b = blockIdx.x * 64 + threadIdx.x;
  const int lt = threadIdx.x;
  const float w0 = w_exc[0], w1 = w_exc[1], wi = w_inh[0];
  const uint4* __restrict__ cb4 = (const uint4*)cbits;

  // Carries buffered in LDS (lgkmcnt domain), flushed once at the end.
  __shared__ float lcar[2 * CHUNKS * 64];  // 16 KB

  float mem = 0.0f, inh = 0.0f;

  uint4 cur = cb4[b];            // group 0
  uint4 nxt = cb4[B_N + b];      // group 1

  for (int g = 0; g < GR; ++g) {                 // dynamic: body stays in I$
    const int gp = (g + 2 < GR) ? (g + 2) : (GR - 1);
    const uint4 pf = cb4[(size_t)gp * B_N + b];  // keep 1-2 loads in flight
    unsigned ws[4] = {cur.x, cur.y, cur.z, cur.w};
#pragma unroll
    for (int j = 0; j < 4; ++j) {
      if ((j & 1) == 0) {                        // word 4g+j even: chunk edge
        const int c = 2 * g + (j >> 1);          // state BEFORE t = c*CLEN
        lcar[(2 * c + 0) * 64 + lt] = mem;
        lcar[(2 * c + 1) * 64 + lt] = inh;
      }
      const unsigned w = ws[j];
#pragma unroll
      for (int u = 0; u < TPW; ++u) {
        const float x0 = (float)((w >> (2 * u)) & 1u);
        const float x1 = (float)((w >> (2 * u + 1)) & 1u);
        neuron_step_core(x0, x1, w0, w1, wi, mem, inh);
      }
    }
    cur = nxt;
    nxt = pf;
  }

  // Flush carries to global once, coalesced.
#pragma unroll
  for (int c = 0; c < CHUNKS; ++c) {
    carry[c * B_N + b]            = lcar[(2 * c + 0) * 64 + lt];
    carry[(CHUNKS + c) * B_N + b] = lcar[(2 * c + 1) * 64 + lt];
  }
}

// ---- Phase 2: per-chunk replay + output streaming (plain stores). ----
__global__ __launch_bounds__(256) void FMFM_emit(
    const unsigned* __restrict__ cbits, const float* __restrict__ w_exc,
    const float* __restrict__ w_inh, const float* __restrict__ carry,
    float* __restrict__ out) {
#pragma clang fp contract(off)
  const int c = blockIdx.x >> 6;                       // 64 neuron-blocks/chunk
  const int b = ((blockIdx.x & 63) << 8) + threadIdx.x;
  const float w0 = w_exc[0], w1 = w_exc[1], wi = w_inh[0];

  float mem = carry[c * B_N + b];
  float inh = carry[(CHUNKS + c) * B_N + b];
  // Chunk c = words 2c, 2c+1 -> group c>>1, dword pair (c&1)*2.
  const uint2 wv = *(const uint2*)&cbits[((size_t)(c >> 1) * B_N + b) * 4 +
                                         (c & 1) * 2];
  const unsigned wa = wv.x, wb = wv.y;

  float* __restrict__ spk_out = out;
  float* __restrict__ mem_out = out + (size_t)T_LEN * B_N;
  const int tbase = c * CLEN;

#pragma unroll
  for (int u = 0; u < CLEN; ++u) {
    const unsigned w = (u < TPW) ? wa : wb;
    const int s = u & (TPW - 1);
    const float x0 = (float)((w >> (2 * s)) & 1u);
    const float x1 = (float)((w >> (2 * s + 1)) & 1u);
    neuron_step_core(x0, x1, w0, w1, wi, mem, inh);
    const float spk = (mem - 1.0f > 0.0f) ? 1.0f : 0.0f;
    const int t = tbase + u;
    spk_out[t * B_N + b] = spk;   // plain stores: L2 write-back aggregation
    mem_out[t * B_N + b] = mem;
  }
}

extern "C" void kernel_launch(void* const* d_in, const int* in_sizes, int n_in,
                              void* d_out, int out_size, void* d_ws, size_t ws_size,
                              hipStream_t stream) {
  const float* x     = (const float*)d_in[0];
  const float* w_exc = (const float*)d_in[1];
  const float* w_inh = (const float*)d_in[2];
  float* out = (float*)d_out;

  unsigned* cbits = (unsigned*)d_ws;                                // 4 MB
  float*    carry = (float*)((char*)d_ws + (size_t)NTC * B_N * 4);  // 4 MB

  hipLaunchKernelGGL(FMFM_pack, dim3(NTC * (B_N / 2) / 256), dim3(256), 0,
                     stream, x, cbits);
  hipLaunchKernelGGL(FMFM_scan, dim3(B_N / 64), dim3(64), 0, stream,
                     cbits, w_exc, w_inh, carry);
  hipLaunchKernelGGL(FMFM_emit, dim3(CHUNKS * (B_N / 256)), dim3(256), 0,
                     stream, cbits, w_exc, w_inh, carry, out);
}